// Round 1
// baseline (608.924 us; speedup 1.0000x reference)
//
#include <hip/hip_runtime.h>
#include <hip/hip_bf16.h>
#include <math.h>

#define NEGINF (-INFINITY)

__device__ __forceinline__ float wave_max_f(float m) {
#pragma unroll
  for (int d = 32; d > 0; d >>= 1) m = fmaxf(m, __shfl_xor(m, d, 64));
  return m;
}
__device__ __forceinline__ float wave_sum_f(float s) {
#pragma unroll
  for (int d = 32; d > 0; d >>= 1) s += __shfl_xor(s, d, 64);
  return s;
}
__device__ __forceinline__ int wave_sum_i(int s) {
#pragma unroll
  for (int d = 32; d > 0; d >>= 1) s += __shfl_xor(s, d, 64);
  return s;
}

// ---------------------------------------------------------------------------
// Kernel A: per (b,t) row of ctc_out[V]: logsumexp, then gather blank+labels.
// Writes lp_compact[B][T][L+1]  (j=0 -> blank(vocab 0), j=1..L -> label j-1)
// ---------------------------------------------------------------------------
__global__ __launch_bounds__(256) void kA_lse_gather(
    const float* __restrict__ ctc_out, const int* __restrict__ ctc_label,
    float* __restrict__ lp_compact, int B, int T, int V, int L)
{
  extern __shared__ float shrow[];  // V floats
  __shared__ float wred[4];
  int row = blockIdx.x;             // b*T + t
  int b = row / T;
  int tid = threadIdx.x;
  int w = tid >> 6;
  const float* x = ctc_out + (size_t)row * V;

  float m = NEGINF;
  if ((V & 3) == 0) {
    int nf4 = V >> 2;
    for (int k = tid; k < nf4; k += 256) {
      float4 v = reinterpret_cast<const float4*>(x)[k];
      reinterpret_cast<float4*>(shrow)[k] = v;
      m = fmaxf(m, fmaxf(fmaxf(v.x, v.y), fmaxf(v.z, v.w)));
    }
  } else {
    for (int k = tid; k < V; k += 256) {
      float v = x[k]; shrow[k] = v; m = fmaxf(m, v);
    }
  }
  m = wave_max_f(m);
  if ((tid & 63) == 0) wred[w] = m;
  __syncthreads();
  float bm = fmaxf(fmaxf(wred[0], wred[1]), fmaxf(wred[2], wred[3]));
  __syncthreads();

  float s = 0.f;
  for (int k = tid; k < V; k += 256) s += __expf(shrow[k] - bm);
  s = wave_sum_f(s);
  if ((tid & 63) == 0) wred[w] = s;
  __syncthreads();
  float lse = bm + __logf(wred[0] + wred[1] + wred[2] + wred[3]);

  float* dst = lp_compact + (size_t)row * (L + 1);
  for (int j = tid; j <= L; j += 256) {
    int vi = (j == 0) ? 0 : ctc_label[(size_t)b * L + (j - 1)];
    if ((unsigned)vi >= (unsigned)V) vi = 0;
    dst[j] = shrow[vi] - lse;
  }
}

// ---------------------------------------------------------------------------
// Kernel B: Viterbi forced alignment, one wave (64 lanes) per batch item.
// Lane l owns states 7l..7l+6. Transition offsets (2b/state, 14b/lane) are
// packed into a u16 per lane per time step, stored in LDS. Backtrace chases
// the offsets in LDS (all lanes redundantly) and records begin frames.
// ---------------------------------------------------------------------------
__global__ __launch_bounds__(64) void kB_viterbi(
    const float* __restrict__ lp_compact, const int* __restrict__ ctc_label,
    float* __restrict__ ali, int B, int T, int L)
{
  extern __shared__ char smem[];
  const int N = 2 * L + 1;
  const int LANES = (N + 6) / 7;
  unsigned short* offrow = reinterpret_cast<unsigned short*>(smem);
  size_t offbytes = ((size_t)(T - 1) * LANES * 2 + 15) & ~(size_t)15;
  float* afin = reinterpret_cast<float*>(smem + offbytes);

  int b = blockIdx.x;
  int lane = threadIdx.x;
  const float* lpb = lp_compact + (size_t)b * T * (L + 1);
  const int* lab = ctc_label + (size_t)b * L;

  int i0 = lane * 7;
  float a[7];
  int tw[7];
  int isodd[7];
  int tlo[7];
  unsigned rng[7];
#pragma unroll
  for (int s = 0; s < 7; ++s) {
    int i = i0 + s;
    bool valid = (i < N);
    bool odd = (i & 1) != 0;
    int li = (i - 1) >> 1;
    int myl = (odd && valid) ? lab[li] : 0;
    int pl  = (odd && valid && i >= 3) ? lab[li - 1] : -1;
    tw[s] = ((!odd) || (i == 1) || (myl == pl)) ? 1 : 0;
    isodd[s] = odd ? 1 : 0;
    if (valid) {
      tlo[s] = (i + 1) >> 1;                 // t >= ceil(i/2)
      int thi = T - L + (i >> 1);            // t <= T-L+floor(i/2)
      rng[s] = (unsigned)(thi - tlo[s]);
    } else {
      tlo[s] = T + 2;
      rng[s] = 0u;
    }
    // t=0 init: only states 0,1 get lp, rest -inf (no feasibility at t=0)
    a[s] = (i == 0) ? lpb[0] : ((i == 1) ? lpb[1] : NEGINF);
  }
  int jbase = (i0 >> 1) + 1;  // lp index of this lane's first odd state

  auto loadrow = [&](int t, float& bl, float* o) {
    const float* r = lpb + (size_t)t * (L + 1);
    bl = r[0];
#pragma unroll
    for (int q = 0; q < 4; ++q) {
      int j = jbase + q;
      if (j > L) j = L;
      o[q] = r[j];
    }
  };

  float bl0, bl1, o0[4], o1[4];
  loadrow(1, bl0, o0);
  loadrow(T > 2 ? 2 : 1, bl1, o1);

  for (int t = 1; t < T; ++t) {
    float t6 = __shfl_up(a[6], 1, 64);  // state 7l-1 (prev lane slot 6)
    float t5 = __shfl_up(a[5], 1, 64);  // state 7l-2 (prev lane slot 5)
    if (lane == 0) { t6 = NEGINF; t5 = NEGINF; }

    float blc = bl0;
    float oc[4] = {o0[0], o0[1], o0[2], o0[3]};
    bl0 = bl1; o0[0] = o1[0]; o0[1] = o1[1]; o0[2] = o1[2]; o0[3] = o1[3];
    if (t + 2 <= T - 1) loadrow(t + 2, bl1, o1);

    unsigned pack = 0;
    float anew[7];
#pragma unroll
    for (int s = 0; s < 7; ++s) {
      float p0 = a[s];
      float p1 = (s == 0) ? t6 : a[s - 1];
      float p2 = (s == 0) ? t5 : ((s == 1) ? t6 : a[s - 2]);
      bool c01 = p0 > p1;
      float m01 = c01 ? p0 : p1;        // ref val_two: tie -> p1
      unsigned off01 = c01 ? 0u : 1u;
      bool c2 = m01 > p2;
      bool take3 = (!tw[s]) && (!c2);
      unsigned offv = take3 ? 2u : off01;
      float asel = take3 ? p2 : m01;
      bool feas = (unsigned)(t - tlo[s]) <= rng[s];
      float lps = isodd[s] ? oc[s >> 1] : blc;
      anew[s] = feas ? (asel + lps) : NEGINF;
      pack |= offv << (2 * s);
    }
    if (lane < LANES)
      offrow[(size_t)(t - 1) * LANES + lane] = (unsigned short)pack;
#pragma unroll
    for (int s = 0; s < 7; ++s) a[s] = anew[s];
  }

#pragma unroll
  for (int s = 0; s < 7; ++s) afin[s * 64 + lane] = a[s];
  __syncthreads();

  int iN1 = N - 1, iN2 = N - 2;
  float vlast = afin[(iN1 % 7) * 64 + (iN1 / 7)];
  float vprev = afin[(iN2 % 7) * 64 + (iN2 / 7)];
  bool use_last = vlast > vprev;
  int pre = use_last ? iN1 : iN2;

  // align regs: lane owns labels {lane, lane+64, lane+128, lane+192}
  float al[4] = {0.f, 0.f, 0.f, 0.f};
#pragma unroll
  for (int r = 0; r < 4; ++r)
    if (!use_last && ((L - 1) >> 6) == r && lane == ((L - 1) & 63))
      al[r] = (float)T;

  for (int t = T - 1; t >= 1; --t) {
    int l7 = pre / 7;
    int s7 = pre - l7 * 7;
    unsigned wv = offrow[(size_t)(t - 1) * LANES + l7];  // broadcast read
    unsigned off = (wv >> (2 * s7)) & 3u;
    pre -= (int)off;
    if (pre & 1) {
      int lbl = pre >> 1;
      int rr = lbl >> 6, ln = lbl & 63;
#pragma unroll
      for (int r = 0; r < 4; ++r)
        if (rr == r && lane == ln) al[r] = (float)t;
    }
  }
#pragma unroll
  for (int r = 0; r < 4; ++r) {
    int l = lane + 64 * r;
    if (l < L) ali[(size_t)b * L + l] = al[r];
  }
}

// ---------------------------------------------------------------------------
// Kernel C: one wave per (b,layer,o<L) row: dot(ali_out_row, pos) - ali,
// masked, squared; 4 rows/block -> per-block partial sum.
// ---------------------------------------------------------------------------
__global__ __launch_bounds__(256) void kC_rows(
    const float* __restrict__ ali_out, const float* __restrict__ ali,
    const int* __restrict__ ali_beg, float* __restrict__ partials,
    int B, int layers, int L, int T)
{
  __shared__ float ps[4];
  int wid = threadIdx.x >> 6, lane = threadIdx.x & 63;
  int row = blockIdx.x * 4 + wid;
  int nrows = B * layers * L;
  float val = 0.f;
  if (row < nrows) {
    int o = row % L;
    int bl = row / L;
    int layer = bl % layers;
    int b = bl / layers;
    const float* x = ali_out + ((size_t)(b * layers + layer) * (L + 1) + o) * T;
    float s = 0.f;
    if ((T & 3) == 0) {
      int nf4 = T >> 2;
      for (int k = lane; k < nf4; k += 64) {
        float4 v = reinterpret_cast<const float4*>(x)[k];
        float base = (float)(4 * k);
        s += v.x * (base + 1.f) + v.y * (base + 2.f) +
             v.z * (base + 3.f) + v.w * (base + 4.f);
      }
    } else {
      for (int k = lane; k < T; k += 64) s += x[k] * (float)(k + 1);
    }
    s = wave_sum_f(s);
    int cnt = 0;
    for (int l = lane; l < L; l += 64)
      cnt += (ali_beg[(size_t)b * L + l] != -1) ? 1 : 0;
    cnt = wave_sum_i(cnt);
    if (lane == 0) {
      float lat = (o >= cnt) ? 0.f : (s - ali[(size_t)b * L + o]);
      val = lat * lat;
    }
  }
  if (lane == 0) ps[wid] = val;
  __syncthreads();
  if (threadIdx.x == 0) partials[blockIdx.x] = ps[0] + ps[1] + ps[2] + ps[3];
}

// ---------------------------------------------------------------------------
// Kernel D: reduce partials, compute total = layers * sum(ylen), write scalar.
// ---------------------------------------------------------------------------
__global__ __launch_bounds__(256) void kD_final(
    const float* __restrict__ partials, int nparts,
    const int* __restrict__ ali_beg, int BL, int layers, int T,
    float* __restrict__ out)
{
  __shared__ float wred[4];
  __shared__ int wcnt[4];
  int tid = threadIdx.x, w = tid >> 6;
  float s = 0.f;
  for (int k = tid; k < nparts; k += 256) s += partials[k];
  s = wave_sum_f(s);
  int c = 0;
  for (int k = tid; k < BL; k += 256) c += (ali_beg[k] != -1) ? 1 : 0;
  c = wave_sum_i(c);
  if ((tid & 63) == 0) { wred[w] = s; wcnt[w] = c; }
  __syncthreads();
  if (tid == 0) {
    float ss = wred[0] + wred[1] + wred[2] + wred[3];
    float total = (float)(wcnt[0] + wcnt[1] + wcnt[2] + wcnt[3]) * (float)layers;
    out[0] = ss / total / (float)T;
  }
}

extern "C" void kernel_launch(void* const* d_in, const int* in_sizes, int n_in,
                              void* d_out, int out_size, void* d_ws, size_t ws_size,
                              hipStream_t stream)
{
  const float* ali_out   = (const float*)d_in[0];
  const int*   ali_beg   = (const int*)d_in[1];
  // d_in[2] ali_end, d_in[3] enc_mask, d_in[6] ctc_len: unused by reference math
  const float* ctc_out   = (const float*)d_in[4];
  const int*   ctc_label = (const int*)d_in[5];

  int B = in_sizes[6];
  int L = in_sizes[1] / B;
  int T = in_sizes[3] / B;
  int V = (int)((long long)in_sizes[4] / ((long long)B * T));
  int layers = (int)((long long)in_sizes[0] / ((long long)B * (L + 1) * T));

  float* lp_compact = (float*)d_ws;
  size_t lp_elems = (size_t)B * T * (L + 1);
  float* ali = lp_compact + lp_elems;
  float* partials = ali + (size_t)B * L;
  int nrows = B * layers * L;
  int gridC = (nrows + 3) / 4;

  // A: logsumexp + gather
  size_t shA = (size_t)V * sizeof(float);
  hipLaunchKernelGGL(kA_lse_gather, dim3(B * T), dim3(256), shA, stream,
                     ctc_out, ctc_label, lp_compact, B, T, V, L);

  // B: Viterbi forward + backtrace (one wave per batch item)
  int N = 2 * L + 1;
  int LANES = (N + 6) / 7;
  size_t offbytes = ((size_t)(T - 1) * LANES * 2 + 15) & ~(size_t)15;
  size_t shB = offbytes + (size_t)64 * 7 * sizeof(float);
  hipFuncSetAttribute(reinterpret_cast<const void*>(kB_viterbi),
                      hipFuncAttributeMaxDynamicSharedMemorySize, (int)shB);
  hipLaunchKernelGGL(kB_viterbi, dim3(B), dim3(64), shB, stream,
                     lp_compact, ctc_label, ali, B, T, L);

  // C: expected-position rows + squared residual partials
  hipLaunchKernelGGL(kC_rows, dim3(gridC), dim3(256), 0, stream,
                     ali_out, ali, ali_beg, partials, B, layers, L, T);

  // D: finalize scalar
  hipLaunchKernelGGL(kD_final, dim3(1), dim3(256), 0, stream,
                     partials, gridC, ali_beg, B * L, layers, T, (float*)d_out);
}

// Round 2
// 525.972 us; speedup vs baseline: 1.1577x; 1.1577x over previous
//
#include <hip/hip_runtime.h>
#include <hip/hip_bf16.h>
#include <math.h>

#define NEGINF (-INFINITY)

__device__ __forceinline__ float wave_max_f(float m) {
#pragma unroll
  for (int d = 32; d > 0; d >>= 1) m = fmaxf(m, __shfl_xor(m, d, 64));
  return m;
}
__device__ __forceinline__ float wave_sum_f(float s) {
#pragma unroll
  for (int d = 32; d > 0; d >>= 1) s += __shfl_xor(s, d, 64);
  return s;
}
__device__ __forceinline__ int wave_sum_i(int s) {
#pragma unroll
  for (int d = 32; d > 0; d >>= 1) s += __shfl_xor(s, d, 64);
  return s;
}

// ---------------------------------------------------------------------------
// Kernel A: per (b,t) row of ctc_out[V]: logsumexp, then gather into the
// forward-friendly layout:
//   lpBlank[b*T + t]                    = lp(blank)
//   lpQuad [(b*T + t)*LANES + s] (f4)   = lp(labels jbase(s)..jbase(s)+3)
// where jbase(s) = (7s>>1)+1, entries clamped to label L.
// ---------------------------------------------------------------------------
__global__ __launch_bounds__(256) void kA_lse_gather(
    const float* __restrict__ ctc_out, const int* __restrict__ ctc_label,
    float* __restrict__ lpBlank, float4* __restrict__ lpQuad,
    int B, int T, int V, int L, int LANES)
{
  extern __shared__ float shrow[];  // V floats
  __shared__ float wred[4];
  int row = blockIdx.x;             // b*T + t
  int b = row / T;
  int tid = threadIdx.x;
  int w = tid >> 6;
  const float* x = ctc_out + (size_t)row * V;

  float m = NEGINF;
  int nf4 = V >> 2;
  for (int k = tid; k < nf4; k += 256) {
    float4 v = reinterpret_cast<const float4*>(x)[k];
    reinterpret_cast<float4*>(shrow)[k] = v;
    m = fmaxf(m, fmaxf(fmaxf(v.x, v.y), fmaxf(v.z, v.w)));
  }
  for (int k = (nf4 << 2) + tid; k < V; k += 256) {
    float v = x[k]; shrow[k] = v; m = fmaxf(m, v);
  }
  m = wave_max_f(m);
  if ((tid & 63) == 0) wred[w] = m;
  __syncthreads();
  float bm = fmaxf(fmaxf(wred[0], wred[1]), fmaxf(wred[2], wred[3]));
  __syncthreads();

  float s = 0.f;
  for (int k = tid; k < V; k += 256) s += __expf(shrow[k] - bm);
  s = wave_sum_f(s);
  if ((tid & 63) == 0) wred[w] = s;
  __syncthreads();
  float lse = bm + __logf(wred[0] + wred[1] + wred[2] + wred[3]);

  const int* lab = ctc_label + (size_t)b * L;
  float* qdst = reinterpret_cast<float*>(lpQuad + (size_t)row * LANES);
  for (int idx = tid; idx < LANES * 4; idx += 256) {
    int sl = idx >> 2, q = idx & 3;
    int jb = ((7 * sl) >> 1) + 1;
    int j = jb + q; if (j > L) j = L;
    int vi = lab[j - 1];
    if ((unsigned)vi >= (unsigned)V) vi = 0;
    qdst[idx] = shrow[vi] - lse;
  }
  if (tid == 0) lpBlank[row] = shrow[0] - lse;
}

// ---------------------------------------------------------------------------
// Kernel B: Viterbi forced alignment, one wave per batch item.
// Lane l owns states 7l..7l+6. Forward: DEPTH=12 register ring of prefetched
// rows (1 dwordx4 + 1 dword per row). Transition offsets (2b/state) packed
// 14b/lane into u16 LDS rows. Backtrace: batched K=7 with speculative
// candidate-group reads so LDS latency amortizes 7x.
// ---------------------------------------------------------------------------
__global__ __launch_bounds__(64, 1) void kB_viterbi(
    const float* __restrict__ lpBlank, const float4* __restrict__ lpQuad,
    const int* __restrict__ ctc_label, float* __restrict__ ali,
    int B, int T, int L)
{
  extern __shared__ char smem[];
  const int N = 2 * L + 1;
  const int LANES = (N + 6) / 7;
  unsigned short* offrow = reinterpret_cast<unsigned short*>(smem);
  size_t offbytes = ((size_t)(T - 1) * LANES * 2 + 15) & ~(size_t)15;
  float* afin = reinterpret_cast<float*>(smem + offbytes);

  int b = blockIdx.x;
  int lane = threadIdx.x;
  const float* blk = lpBlank + (size_t)b * T;
  const float4* qd = lpQuad + (size_t)b * T * LANES;
  const int* lab = ctc_label + (size_t)b * L;
  int qlane = (lane < LANES) ? lane : (LANES - 1);

  int i0 = lane * 7;
  float a[7];
  int twv[7];
  int tlo[7];
  unsigned rng[7];
#pragma unroll
  for (int s = 0; s < 7; ++s) {
    int i = i0 + s;
    bool valid = (i < N);
    bool odd = (i & 1) != 0;
    int li = (i - 1) >> 1;
    int myl = (odd && valid) ? lab[li] : 0;
    int pl  = (odd && valid && i >= 3) ? lab[li - 1] : -1;
    twv[s] = ((!odd) || (i == 1) || (myl == pl)) ? 1 : 0;
    if (valid) {
      tlo[s] = (i + 1) >> 1;                 // t >= ceil(i/2)
      int thi = T - L + (i >> 1);            // t <= T-L+floor(i/2)
      rng[s] = (unsigned)(thi - tlo[s]);
    } else {
      tlo[s] = T + 2;
      rng[s] = 0u;
    }
  }

  // t=0 init: only states 0,1 get lp, rest -inf
  float bl00 = blk[0];
  float4 q00 = qd[qlane];
#pragma unroll
  for (int s = 0; s < 7; ++s) {
    int i = i0 + s;
    a[s] = (i == 0) ? bl00 : ((i == 1) ? q00.x : NEGINF);
  }

  const int DEPTH = 12;
  float rbl[DEPTH];
  float4 rq[DEPTH];
#pragma unroll
  for (int u = 0; u < DEPTH; ++u) {
    int r = 1 + u; if (r > T - 1) r = T - 1;
    rbl[u] = blk[r];
    rq[u] = qd[(size_t)r * LANES + qlane];
  }

#define KB_BODY(u, FEAS)                                                      \
  {                                                                           \
    float blc = rbl[u];                                                       \
    float4 oc = rq[u];                                                        \
    int pf = tt + DEPTH; if (pf > T - 1) pf = T - 1;                          \
    rbl[u] = blk[pf];                                                         \
    rq[u] = qd[(size_t)pf * LANES + qlane];                                   \
    float t6 = __shfl_up(a[6], 1, 64);                                        \
    float t5 = __shfl_up(a[5], 1, 64);                                        \
    if (lane == 0) { t6 = NEGINF; t5 = NEGINF; }                              \
    unsigned pack = 0;                                                        \
    float anew[7];                                                            \
    _Pragma("unroll")                                                         \
    for (int s = 0; s < 7; ++s) {                                             \
      float p0 = a[s];                                                        \
      float p1 = (s == 0) ? t6 : a[s - 1];                                    \
      float p2 = (s == 0) ? t5 : ((s == 1) ? t6 : a[s - 2]);                  \
      bool c01 = p0 > p1;                                                     \
      float m01 = c01 ? p0 : p1;                                              \
      bool c2 = m01 > p2;                                                     \
      bool take3 = (twv[s] == 0) && (!c2);                                    \
      float asel = take3 ? p2 : m01;                                          \
      unsigned ox = c01 ? 0u : 1u;                                            \
      unsigned offv = take3 ? 2u : ox;                                        \
      float ocs = (s < 2) ? oc.x : ((s < 4) ? oc.y : ((s < 6) ? oc.z : oc.w));\
      float lps = (((lane ^ s) & 1) != 0) ? ocs : blc;                        \
      float av = asel + lps;                                                  \
      if (FEAS) {                                                             \
        bool feas = (unsigned)(tt - tlo[s]) <= rng[s];                        \
        av = feas ? av : NEGINF;                                              \
      }                                                                       \
      anew[s] = av;                                                           \
      pack |= offv << (2 * s);                                                \
    }                                                                         \
    if (lane < LANES)                                                         \
      offrow[(size_t)(tt - 1) * LANES + lane] = (unsigned short)pack;         \
    _Pragma("unroll")                                                         \
    for (int s = 0; s < 7; ++s) a[s] = anew[s];                               \
  }

  for (int t0 = 1; t0 < T; t0 += DEPTH) {
    bool fastc = (t0 >= L) && (t0 + DEPTH - 1 <= T - L) && (t0 + DEPTH <= T);
    if (fastc) {
#pragma unroll
      for (int u = 0; u < DEPTH; ++u) {
        int tt = t0 + u;
        KB_BODY(u, false)
      }
    } else {
#pragma unroll
      for (int u = 0; u < DEPTH; ++u) {
        int tt = t0 + u;
        if (tt < T) {
          KB_BODY(u, true)
        }
      }
    }
  }
#undef KB_BODY

#pragma unroll
  for (int s = 0; s < 7; ++s) afin[s * 64 + lane] = a[s];
  __syncthreads();

  int iN1 = N - 1, iN2 = N - 2;
  float vlast = afin[(iN1 % 7) * 64 + (iN1 / 7)];
  float vprev = afin[(iN2 % 7) * 64 + (iN2 / 7)];
  bool use_last = vlast > vprev;
  int pre = use_last ? iN1 : iN2;

  float al[4] = {0.f, 0.f, 0.f, 0.f};
  {
    int lbl = L - 1; int rr = lbl >> 6, ln = lbl & 63;
#pragma unroll
    for (int r = 0; r < 4; ++r)
      if (!use_last && rr == r && lane == ln) al[r] = (float)T;
  }

  // Backtrace: batches of K<=7 steps. State tracked as (g, mm): pre = 7g+mm.
  int t = T - 1;
  int g = pre / 7, mm = pre - g * 7;
  while (t >= 1) {
    int K = (t < 7) ? t : 7;
    int pcur = g * 7 + mm;
    int gmax = g;
    unsigned short w0v = offrow[(size_t)(t - 1) * LANES + g];
    unsigned short cw[7][3];
    int gmn[7];
#pragma unroll
    for (int j = 1; j < 7; ++j) {
      if (j < K) {
        int lo = pcur - 2 * j; if (lo < 0) lo = 0;
        int gm = lo / 7;
        gmn[j] = gm;
#pragma unroll
        for (int r = 0; r < 3; ++r) {
          int gg = gm + r; if (gg > gmax) gg = gmax;
          cw[j][r] = offrow[(size_t)(t - 1 - j) * LANES + gg];
        }
      }
    }
#pragma unroll
    for (int j = 0; j < 7; ++j) {
      if (j < K) {
        unsigned w;
        if (j == 0) {
          w = w0v;
        } else {
          int gi = g - gmn[j];
          unsigned wa = cw[j][0], wb = cw[j][1], wc2 = cw[j][2];
          w = (gi == 0) ? wa : ((gi == 1) ? wb : wc2);
        }
        unsigned off = (w >> (2 * mm)) & 3u;
        mm -= (int)off;
        bool bor = mm < 0;
        g = bor ? (g - 1) : g;
        mm = bor ? (mm + 7) : mm;
        int cur = g * 7 + mm;
        if (cur & 1) {
          int lbl = cur >> 1;
          int rr = lbl >> 6, ln = lbl & 63;
#pragma unroll
          for (int r = 0; r < 4; ++r)
            if (rr == r && lane == ln) al[r] = (float)(t - j);
        }
      }
    }
    t -= K;
  }

#pragma unroll
  for (int r = 0; r < 4; ++r) {
    int l = lane + 64 * r;
    if (l < L) ali[(size_t)b * L + l] = al[r];
  }
}

// ---------------------------------------------------------------------------
// Kernel C: one wave per (b,layer,o<L) row: dot(ali_out_row, pos) - ali,
// masked, squared; 4 rows/block -> per-block partial sum.
// ---------------------------------------------------------------------------
__global__ __launch_bounds__(256) void kC_rows(
    const float* __restrict__ ali_out, const float* __restrict__ ali,
    const int* __restrict__ ali_beg, float* __restrict__ partials,
    int B, int layers, int L, int T)
{
  __shared__ float ps[4];
  int wid = threadIdx.x >> 6, lane = threadIdx.x & 63;
  int row = blockIdx.x * 4 + wid;
  int nrows = B * layers * L;
  float val = 0.f;
  if (row < nrows) {
    int o = row % L;
    int bl = row / L;
    int layer = bl % layers;
    int b = bl / layers;
    const float* x = ali_out + ((size_t)(b * layers + layer) * (L + 1) + o) * T;
    float s = 0.f;
    if ((T & 3) == 0) {
      int nf4 = T >> 2;
      for (int k = lane; k < nf4; k += 64) {
        float4 v = reinterpret_cast<const float4*>(x)[k];
        float base = (float)(4 * k);
        s += v.x * (base + 1.f) + v.y * (base + 2.f) +
             v.z * (base + 3.f) + v.w * (base + 4.f);
      }
    } else {
      for (int k = lane; k < T; k += 64) s += x[k] * (float)(k + 1);
    }
    s = wave_sum_f(s);
    int cnt = 0;
    for (int l = lane; l < L; l += 64)
      cnt += (ali_beg[(size_t)b * L + l] != -1) ? 1 : 0;
    cnt = wave_sum_i(cnt);
    if (lane == 0) {
      float lat = (o >= cnt) ? 0.f : (s - ali[(size_t)b * L + o]);
      val = lat * lat;
    }
  }
  if (lane == 0) ps[wid] = val;
  __syncthreads();
  if (threadIdx.x == 0) partials[blockIdx.x] = ps[0] + ps[1] + ps[2] + ps[3];
}

// ---------------------------------------------------------------------------
// Kernel D: reduce partials, compute total = layers * sum(ylen), write scalar.
// ---------------------------------------------------------------------------
__global__ __launch_bounds__(256) void kD_final(
    const float* __restrict__ partials, int nparts,
    const int* __restrict__ ali_beg, int BL, int layers, int T,
    float* __restrict__ out)
{
  __shared__ float wred[4];
  __shared__ int wcnt[4];
  int tid = threadIdx.x, w = tid >> 6;
  float s = 0.f;
  for (int k = tid; k < nparts; k += 256) s += partials[k];
  s = wave_sum_f(s);
  int c = 0;
  for (int k = tid; k < BL; k += 256) c += (ali_beg[k] != -1) ? 1 : 0;
  c = wave_sum_i(c);
  if ((tid & 63) == 0) { wred[w] = s; wcnt[w] = c; }
  __syncthreads();
  if (tid == 0) {
    float ss = wred[0] + wred[1] + wred[2] + wred[3];
    float total = (float)(wcnt[0] + wcnt[1] + wcnt[2] + wcnt[3]) * (float)layers;
    out[0] = ss / total / (float)T;
  }
}

extern "C" void kernel_launch(void* const* d_in, const int* in_sizes, int n_in,
                              void* d_out, int out_size, void* d_ws, size_t ws_size,
                              hipStream_t stream)
{
  const float* ali_out   = (const float*)d_in[0];
  const int*   ali_beg   = (const int*)d_in[1];
  // d_in[2] ali_end, d_in[3] enc_mask, d_in[6] ctc_len: unused by reference math
  const float* ctc_out   = (const float*)d_in[4];
  const int*   ctc_label = (const int*)d_in[5];

  int B = in_sizes[6];
  int L = in_sizes[1] / B;
  int T = in_sizes[3] / B;
  int V = (int)((long long)in_sizes[4] / ((long long)B * T));
  int layers = (int)((long long)in_sizes[0] / ((long long)B * (L + 1) * T));

  int N = 2 * L + 1;
  int LANES = (N + 6) / 7;

  // workspace layout
  float* lpBlank = (float*)d_ws;                          // B*T
  float4* lpQuad = (float4*)(lpBlank + (size_t)B * T);    // B*T*LANES float4
  float* ali = (float*)(lpQuad + (size_t)B * T * LANES);  // B*L
  float* partials = ali + (size_t)B * L;
  int nrows = B * layers * L;
  int gridC = (nrows + 3) / 4;

  // A: logsumexp + gather into (blank, quad) layout
  size_t shA = (size_t)V * sizeof(float);
  hipLaunchKernelGGL(kA_lse_gather, dim3(B * T), dim3(256), shA, stream,
                     ctc_out, ctc_label, lpBlank, lpQuad, B, T, V, L, LANES);

  // B: Viterbi forward + backtrace (one wave per batch item)
  size_t offbytes = ((size_t)(T - 1) * LANES * 2 + 15) & ~(size_t)15;
  size_t shB = offbytes + (size_t)64 * 7 * sizeof(float);
  hipFuncSetAttribute(reinterpret_cast<const void*>(kB_viterbi),
                      hipFuncAttributeMaxDynamicSharedMemorySize, (int)shB);
  hipLaunchKernelGGL(kB_viterbi, dim3(B), dim3(64), shB, stream,
                     lpBlank, lpQuad, ctc_label, ali, B, T, L);

  // C: expected-position rows + squared residual partials
  hipLaunchKernelGGL(kC_rows, dim3(gridC), dim3(256), 0, stream,
                     ali_out, ali, ali_beg, partials, B, layers, L, T);

  // D: finalize scalar
  hipLaunchKernelGGL(kD_final, dim3(1), dim3(256), 0, stream,
                     partials, gridC, ali_beg, B * L, layers, T, (float*)d_out);
}